// Round 2
// baseline (43.292 us; speedup 1.0000x reference)
//
#include <hip/hip_runtime.h>

#define DEV __device__ __forceinline__

typedef short s16x8 __attribute__((ext_vector_type(8)));
typedef float f32x16 __attribute__((ext_vector_type(16)));

DEV unsigned cvt_pk_bf16(float lo, float hi) {
  unsigned r;
  asm volatile("v_cvt_pk_bf16_f32 %0, %1, %2" : "=v"(r) : "v"(lo), "v"(hi));
  return r;
}

DEV unsigned short f2bf(float f) {
  unsigned u = __builtin_bit_cast(unsigned, f);
  unsigned r = u + 0x7fffu + ((u >> 16) & 1u);
  return (unsigned short)(r >> 16);
}

DEV f32x16 zero16() {
  f32x16 v;
  #pragma unroll
  for (int i = 0; i < 16; ++i) v[i] = 0.f;
  return v;
}

DEV void stage_wt(const float* __restrict__ src, unsigned short* dst, int t) {
  // src: [64 f][64 g] f32 row-major -> dst: [g][f] bf16, 16B-chunk XOR swizzle
  #pragma unroll
  for (int r = 0; r < 4; ++r) {
    int e = (r * 256 + t) * 4;
    int f = e >> 6, g0 = e & 63;
    float4 v = *(const float4*)(src + f * 64 + g0);
    float vv[4] = {v.x, v.y, v.z, v.w};
    #pragma unroll
    for (int j = 0; j < 4; ++j) {
      int g = g0 + j;
      dst[g * 64 + ((((f >> 3) ^ (g & 7)) << 3) | (f & 7))] = f2bf(vv[j]);
    }
  }
}

// ---------------- kernel 1: projections ----------------
// Q = bf16((X@attW) * scale), K = bf16(X@attW), Vt = bf16(X@W) transposed per batch,
// d_out = X@selfW + bias
__global__ __launch_bounds__(256) void prep_kernel(
    const float* __restrict__ X, const float* __restrict__ W,
    const float* __restrict__ attW, const float* __restrict__ Aa,
    const float* __restrict__ biasW, const float* __restrict__ selfW,
    unsigned short* __restrict__ Qbf, unsigned short* __restrict__ Kbf,
    unsigned short* __restrict__ Vt, float* __restrict__ baseO) {
  __shared__ __align__(16) unsigned short Xl[128 * 64];
  __shared__ __align__(16) unsigned short Wt[3][64 * 64];
  __shared__ float scal[64];

  const int t = threadIdx.x;
  const int r0 = blockIdx.x * 128;  // global row base (flat over B*N)
  const int b = r0 >> 10;
  const int n0 = r0 & 1023;

  if (t < 64) {
    float s = 0.f;
    #pragma unroll 8
    for (int i = 0; i < 64; ++i) s += Aa[i * 64 + t];
    scal[t] = s;
  }

  // stage X tile 128x64 f32 -> bf16 swizzled
  #pragma unroll
  for (int r = 0; r < 4; ++r) {
    int e = (r * 256 + t) * 8;
    int row = e >> 6;
    int chunk = (e >> 3) & 7;
    const float4* src = (const float4*)(X + (size_t)(r0 + row) * 64 + chunk * 8);
    float4 a0 = src[0], a1 = src[1];
    unsigned* dst = (unsigned*)&Xl[row * 64 + ((chunk ^ (row & 7)) << 3)];
    dst[0] = cvt_pk_bf16(a0.x, a0.y);
    dst[1] = cvt_pk_bf16(a0.z, a0.w);
    dst[2] = cvt_pk_bf16(a1.x, a1.y);
    dst[3] = cvt_pk_bf16(a1.z, a1.w);
  }

  stage_wt(attW, &Wt[0][0], t);
  stage_wt(W, &Wt[1][0], t);
  stage_wt(selfW, &Wt[2][0], t);
  __syncthreads();

  const int lane = t & 63, w = t >> 6, h = lane >> 5, ln = lane & 31;
  const int rowbase = w * 32;

  s16x8 xa[4];
  #pragma unroll
  for (int ks = 0; ks < 4; ++ks) {
    int row = rowbase + ln;
    int chunk = ks * 2 + h;
    xa[ks] = *(const s16x8*)&Xl[row * 64 + ((chunk ^ (row & 7)) << 3)];
  }

  #pragma unroll
  for (int cf = 0; cf < 2; ++cf) {
    f32x16 aA = zero16(), aW = zero16(), aS = zero16();
    #pragma unroll
    for (int ks = 0; ks < 4; ++ks) {
      int g = cf * 32 + ln, chunk = ks * 2 + h;
      int off = g * 64 + ((chunk ^ (g & 7)) << 3);
      s16x8 bA = *(const s16x8*)&Wt[0][off];
      s16x8 bW = *(const s16x8*)&Wt[1][off];
      s16x8 bS = *(const s16x8*)&Wt[2][off];
      aA = __builtin_amdgcn_mfma_f32_32x32x16_bf16(xa[ks], bA, aA, 0, 0, 0);
      aW = __builtin_amdgcn_mfma_f32_32x32x16_bf16(xa[ks], bW, aW, 0, 0, 0);
      aS = __builtin_amdgcn_mfma_f32_32x32x16_bf16(xa[ks], bS, aS, 0, 0, 0);
    }
    int d = cf * 32 + ln;
    float sc = scal[d];
    float bi = biasW[d];
    #pragma unroll
    for (int reg = 0; reg < 16; ++reg) {
      int rl = (reg & 3) + 8 * (reg >> 2) + 4 * h;
      size_t go = (size_t)(r0 + rowbase + rl) * 64 + d;
      Kbf[go] = f2bf(aA[reg]);
      Qbf[go] = f2bf(aA[reg] * sc);
      baseO[go] = aS[reg] + bi;
    }
    #pragma unroll
    for (int pg = 0; pg < 4; ++pg) {
      int nl = n0 + rowbase + pg * 8 + 4 * h;
      unsigned p0 = cvt_pk_bf16(aW[pg * 4 + 0], aW[pg * 4 + 1]);
      unsigned p1 = cvt_pk_bf16(aW[pg * 4 + 2], aW[pg * 4 + 3]);
      unsigned* vp = (unsigned*)&Vt[((size_t)(b * 64 + d)) * 1024 + nl];
      vp[0] = p0;
      vp[1] = p1;
    }
  }
}

// ---------------- kernel 2: fused S = leaky(mask(Q K^T)); H += S @ V ----------------
__global__ __launch_bounds__(256) void attn_kernel(
    const unsigned short* __restrict__ Qbf, const unsigned short* __restrict__ Kbf,
    const unsigned short* __restrict__ Vt, float* __restrict__ Hout) {
  __shared__ __align__(16) unsigned short Kl[64 * 64];
  __shared__ __align__(16) unsigned short Vl[64 * 64];
  __shared__ float Ol[128 * 65];

  const int t = threadIdx.x;
  const int q0 = blockIdx.x * 128;  // q tile within batch
  const int b = blockIdx.y;
  const int lane = t & 63, w = t >> 6, h = lane >> 5, ln = lane & 31;

  const int qg = q0 + w * 32 + ln;  // this lane's q row (within batch)
  s16x8 qf[4];
  #pragma unroll
  for (int ks = 0; ks < 4; ++ks)
    qf[ks] = *(const s16x8*)(Qbf + ((size_t)(b * 1024 + qg)) * 64 + ks * 16 + h * 8);

  f32x16 o[2];
  o[0] = zero16();
  o[1] = zero16();

  const unsigned short* Kg = Kbf + (size_t)b * 1024 * 64;
  const unsigned short* Vg = Vt + (size_t)b * 64 * 1024;

  for (int kv0 = 0; kv0 < 1024; kv0 += 64) {
    __syncthreads();
    #pragma unroll
    for (int r = 0; r < 2; ++r) {
      int c = r * 256 + t;  // 16B chunk id, 512 per tile
      int row = c >> 3, ck = c & 7;
      s16x8 kk = *(const s16x8*)(Kg + (size_t)(kv0 + row) * 64 + ck * 8);
      *(s16x8*)&Kl[row * 64 + ((ck ^ (row & 7)) << 3)] = kk;
      s16x8 vv = *(const s16x8*)(Vg + (size_t)row * 1024 + kv0 + ck * 8);
      *(s16x8*)&Vl[row * 64 + ((ck ^ (row & 7)) << 3)] = vv;
    }
    __syncthreads();

    unsigned pw[2][2][4];  // [rf_kv][kstep16][word] -> P^T B-frag words
    #pragma unroll
    for (int rf = 0; rf < 2; ++rf) {
      f32x16 s = zero16();
      #pragma unroll
      for (int ks = 0; ks < 4; ++ks) {
        int row = rf * 32 + ln, chunk = ks * 2 + h;
        s16x8 kf = *(const s16x8*)&Kl[row * 64 + ((chunk ^ (row & 7)) << 3)];
        s = __builtin_amdgcn_mfma_f32_32x32x16_bf16(kf, qf[ks], s, 0, 0, 0);
      }
      float p[16];
      #pragma unroll
      for (int reg = 0; reg < 16; ++reg) {
        int kvg = kv0 + rf * 32 + (reg & 3) + 8 * (reg >> 2) + 4 * h;
        float v = s[reg];
        v = v > 0.f ? v : 0.01f * v;
        p[reg] = (kvg == qg) ? 0.f : v;  // zero diagonal; leaky(0)=0 so order is equivalent
      }
      unsigned pk[8];
      #pragma unroll
      for (int i = 0; i < 8; ++i) pk[i] = cvt_pk_bf16(p[2 * i], p[2 * i + 1]);
      auto s0 = __builtin_amdgcn_permlane32_swap(pk[0], pk[2], false, false);
      auto s1 = __builtin_amdgcn_permlane32_swap(pk[1], pk[3], false, false);
      auto s2 = __builtin_amdgcn_permlane32_swap(pk[4], pk[6], false, false);
      auto s3 = __builtin_amdgcn_permlane32_swap(pk[5], pk[7], false, false);
      pw[rf][0][0] = s0[0]; pw[rf][0][1] = s1[0]; pw[rf][0][2] = s0[1]; pw[rf][0][3] = s1[1];
      pw[rf][1][0] = s2[0]; pw[rf][1][1] = s3[0]; pw[rf][1][2] = s2[1]; pw[rf][1][3] = s3[1];
    }
    #pragma unroll
    for (int rfd = 0; rfd < 2; ++rfd) {
      #pragma unroll
      for (int kk = 0; kk < 4; ++kk) {
        int row = rfd * 32 + ln, chunk = kk * 2 + h;
        s16x8 vf = *(const s16x8*)&Vl[row * 64 + ((chunk ^ (row & 7)) << 3)];
        union { unsigned u[4]; s16x8 v; } pb;
        pb.u[0] = pw[kk >> 1][kk & 1][0];
        pb.u[1] = pw[kk >> 1][kk & 1][1];
        pb.u[2] = pw[kk >> 1][kk & 1][2];
        pb.u[3] = pw[kk >> 1][kk & 1][3];
        o[rfd] = __builtin_amdgcn_mfma_f32_32x32x16_bf16(vf, pb.v, o[rfd], 0, 0, 0);
      }
    }
  }

  // epilogue: O^T (regs) -> LDS -> coalesced float4 RMW with base in d_out
  __syncthreads();
  #pragma unroll
  for (int rf = 0; rf < 2; ++rf) {
    #pragma unroll
    for (int reg = 0; reg < 16; ++reg) {
      int dd = rf * 32 + (reg & 3) + 8 * (reg >> 2) + 4 * h;
      Ol[(w * 32 + ln) * 65 + dd] = o[rf][reg];
    }
  }
  __syncthreads();
  #pragma unroll
  for (int i = 0; i < 8; ++i) {
    int fi = i * 256 + t;
    int q = fi >> 4, dw = (fi & 15) * 4;
    float4 v = {Ol[q * 65 + dw], Ol[q * 65 + dw + 1], Ol[q * 65 + dw + 2], Ol[q * 65 + dw + 3]};
    float4* gp = (float4*)(Hout + ((size_t)(b * 1024 + q0 + q)) * 64 + dw);
    float4 base = *gp;
    v.x += base.x; v.y += base.y; v.z += base.z; v.w += base.w;
    *gp = v;
  }
}

extern "C" void kernel_launch(void* const* d_in, const int* in_sizes, int n_in,
                              void* d_out, int out_size, void* d_ws, size_t ws_size,
                              hipStream_t stream) {
  const float* X = (const float*)d_in[0];
  // d_in[1] = A : unused by the forward pass
  const float* W = (const float*)d_in[2];
  const float* attW = (const float*)d_in[3];
  const float* a = (const float*)d_in[4];
  const float* biasW = (const float*)d_in[5];
  const float* selfW = (const float*)d_in[6];
  float* H = (float*)d_out;

  unsigned short* Qbf = (unsigned short*)d_ws;
  unsigned short* Kbf = Qbf + (size_t)32 * 1024 * 64;
  unsigned short* Vt = Kbf + (size_t)32 * 1024 * 64;

  prep_kernel<<<256, 256, 0, stream>>>(X, W, attW, a, biasW, selfW, Qbf, Kbf, Vt, H);
  attn_kernel<<<dim3(8, 32), 256, 0, stream>>>(Qbf, Kbf, Vt, H);
}

// Round 3
// 36.308 us; speedup vs baseline: 1.1924x; 1.1924x over previous
//
#include <hip/hip_runtime.h>

#define DEV __device__ __forceinline__
typedef short s16x8 __attribute__((ext_vector_type(8)));
typedef float f32x16 __attribute__((ext_vector_type(16)));
typedef unsigned short u16;

#define WAIT_VMCNT(N) asm volatile("s_waitcnt vmcnt(" #N ")" ::: "memory")
#define CFENCE asm volatile("" ::: "memory")

DEV unsigned cvt_pk_bf16(float lo, float hi) {
  unsigned r;
  asm volatile("v_cvt_pk_bf16_f32 %0, %1, %2" : "=v"(r) : "v"(lo), "v"(hi));
  return r;
}
DEV u16 f2bf(float f) {
  unsigned u = __builtin_bit_cast(unsigned, f);
  unsigned r = u + 0x7fffu + ((u >> 16) & 1u);
  return (u16)(r >> 16);
}
DEV float bf2f(u16 u) { return __builtin_bit_cast(float, (unsigned)u << 16); }
DEV f32x16 zero16() {
  f32x16 v;
  #pragma unroll
  for (int i = 0; i < 16; ++i) v[i] = 0.f;
  return v;
}

// async global->LDS: 16B per lane, LDS dest must be wave-uniform base + lane*16
DEV void gld16(const u16* g, u16* l) {
  __builtin_amdgcn_global_load_lds(
      (const __attribute__((address_space(1))) void*)g,
      (__attribute__((address_space(3))) void*)l, 16, 0, 0);
}

// stage a 64-row x 64-col bf16 tile (row stride `stride` elems) into swizzled LDS.
// LDS slot s of row r holds global chunk (s ^ (r&7)) -> read with frag().
DEV void stage_tile64(const u16* __restrict__ gbase, size_t stride, u16* lbuf, int t) {
  #pragma unroll
  for (int p = 0; p < 2; ++p) {
    int c = p * 256 + t;
    int row = c >> 3, s = c & 7;
    int gck = s ^ (row & 7);
    const u16* src = gbase + (size_t)row * stride + gck * 8;
    u16* dst = lbuf + (size_t)(p * 256 + (t & 192)) * 8;  // wave-uniform base
    gld16(src, dst);
  }
}

DEV s16x8 frag(const u16* buf, int row, int chunk) {
  return *(const s16x8*)(buf + row * 64 + ((chunk ^ (row & 7)) << 3));
}

DEV void stage_wt(const float* __restrict__ src, u16* dst, int t) {
  // src: [64 f][64 g] f32 row-major -> dst: [g][f] bf16, 16B-chunk XOR swizzle
  #pragma unroll
  for (int r = 0; r < 4; ++r) {
    int e = (r * 256 + t) * 4;
    int f = e >> 6, g0 = e & 63;
    float4 v = *(const float4*)(src + f * 64 + g0);
    float vv[4] = {v.x, v.y, v.z, v.w};
    #pragma unroll
    for (int j = 0; j < 4; ++j) {
      int g = g0 + j;
      dst[g * 64 + ((((f >> 3) ^ (g & 7)) << 3) | (f & 7))] = f2bf(vv[j]);
    }
  }
}

// ---------------- kernel 1: projections ----------------
// Kbf = bf16(X@attW) row-major; Vt = bf16(X@W) transposed [b][d][n];
// Bb = bf16(X@selfW + bias); scal_ws = a.sum(0)
__global__ __launch_bounds__(256) void prep_kernel(
    const float* __restrict__ X, const float* __restrict__ W,
    const float* __restrict__ attW, const float* __restrict__ Aa,
    const float* __restrict__ biasW, const float* __restrict__ selfW,
    u16* __restrict__ Kbf, u16* __restrict__ Vt, u16* __restrict__ Bb,
    float* __restrict__ scal_ws) {
  __shared__ __align__(16) u16 Xl[128 * 64];
  __shared__ __align__(16) u16 Wt[3][64 * 64];
  __shared__ float sc4[4][64];
  __shared__ __align__(16) u16 Kl[128 * 64];
  __shared__ __align__(16) u16 Bl[128 * 64];
  __shared__ __align__(16) u16 Vl[64 * 136];  // 272B row stride: 16B-aligned

  const int t = threadIdx.x;
  const int r0 = blockIdx.x * 128;
  const int b = r0 >> 10;
  const int n0 = r0 & 1023;

  {  // scale = a.sum(axis=0), 4-way split
    int qt = t >> 6, d = t & 63;
    float s = 0.f;
    #pragma unroll
    for (int i = 0; i < 16; ++i) s += Aa[(qt * 16 + i) * 64 + d];
    sc4[qt][d] = s;
  }

  // stage X tile 128x64 f32 -> bf16 swizzled
  #pragma unroll
  for (int r = 0; r < 4; ++r) {
    int e = (r * 256 + t) * 8;
    int row = e >> 6;
    int chunk = (e >> 3) & 7;
    const float4* src = (const float4*)(X + (size_t)(r0 + row) * 64 + chunk * 8);
    float4 a0 = src[0], a1 = src[1];
    unsigned* dst = (unsigned*)&Xl[row * 64 + ((chunk ^ (row & 7)) << 3)];
    dst[0] = cvt_pk_bf16(a0.x, a0.y);
    dst[1] = cvt_pk_bf16(a0.z, a0.w);
    dst[2] = cvt_pk_bf16(a1.x, a1.y);
    dst[3] = cvt_pk_bf16(a1.z, a1.w);
  }
  stage_wt(attW, &Wt[0][0], t);
  stage_wt(W, &Wt[1][0], t);
  stage_wt(selfW, &Wt[2][0], t);
  __syncthreads();

  const int lane = t & 63, w = t >> 6, h = lane >> 5, ln = lane & 31;
  const int rowbase = w * 32;

  s16x8 xa[4];
  #pragma unroll
  for (int ks = 0; ks < 4; ++ks) {
    int row = rowbase + ln;
    xa[ks] = frag(Xl, row, ks * 2 + h);
  }

  #pragma unroll
  for (int cf = 0; cf < 2; ++cf) {
    f32x16 aA = zero16(), aW = zero16(), aS = zero16();
    #pragma unroll
    for (int ks = 0; ks < 4; ++ks) {
      int g = cf * 32 + ln;
      s16x8 bA = frag(&Wt[0][0], g, ks * 2 + h);
      s16x8 bW = frag(&Wt[1][0], g, ks * 2 + h);
      s16x8 bS = frag(&Wt[2][0], g, ks * 2 + h);
      aA = __builtin_amdgcn_mfma_f32_32x32x16_bf16(xa[ks], bA, aA, 0, 0, 0);
      aW = __builtin_amdgcn_mfma_f32_32x32x16_bf16(xa[ks], bW, aW, 0, 0, 0);
      aS = __builtin_amdgcn_mfma_f32_32x32x16_bf16(xa[ks], bS, aS, 0, 0, 0);
    }
    int d = cf * 32 + ln;
    float bi = biasW[d];
    #pragma unroll
    for (int reg = 0; reg < 16; ++reg) {
      int rl = (reg & 3) + 8 * (reg >> 2) + 4 * h;
      int row = rowbase + rl;
      Kl[row * 64 + d] = f2bf(aA[reg]);
      Bl[row * 64 + d] = f2bf(aS[reg] + bi);
    }
    #pragma unroll
    for (int pg = 0; pg < 4; ++pg) {
      int n = rowbase + pg * 8 + 4 * h;
      *(unsigned*)&Vl[d * 136 + n] = cvt_pk_bf16(aW[pg * 4 + 0], aW[pg * 4 + 1]);
      *(unsigned*)&Vl[d * 136 + n + 2] = cvt_pk_bf16(aW[pg * 4 + 2], aW[pg * 4 + 3]);
    }
  }
  __syncthreads();

  // vectorized global writes
  #pragma unroll
  for (int pass = 0; pass < 4; ++pass) {
    int c = pass * 256 + t;
    int row = c >> 3, ck = c & 7;
    size_t go = (size_t)(r0 + row) * 64 + ck * 8;
    *(s16x8*)&Kbf[go] = *(const s16x8*)&Kl[row * 64 + ck * 8];
    *(s16x8*)&Bb[go] = *(const s16x8*)&Bl[row * 64 + ck * 8];
  }
  #pragma unroll
  for (int pass = 0; pass < 4; ++pass) {
    int c = pass * 256 + t;
    int d = c >> 4, ck = c & 15;
    *(s16x8*)&Vt[(size_t)(b * 64 + d) * 1024 + n0 + ck * 8] =
        *(const s16x8*)&Vl[d * 136 + ck * 8];
  }
  if (t < 64) scal_ws[t] = sc4[0][t] + sc4[1][t] + sc4[2][t] + sc4[3][t];
}

// P-processing: leaky + optional diag-zero + pack to P^T B-frag words
#define PROC(SV, DG, PWV)                                                      \
  do {                                                                         \
    float p_[16];                                                              \
    _Pragma("unroll") for (int r_ = 0; r_ < 16; ++r_) {                        \
      float v_ = (SV)[r_];                                                     \
      p_[r_] = fmaxf(v_, 0.f) + 0.01f * fminf(v_, 0.f);                        \
    }                                                                          \
    if (DG) {                                                                  \
      _Pragma("unroll") for (int r_ = 0; r_ < 16; ++r_) {                      \
        int rl_ = (r_ & 3) + 8 * (r_ >> 2) + 4 * h;                            \
        p_[r_] = (rl_ == ln) ? 0.f : p_[r_];                                   \
      }                                                                        \
    }                                                                          \
    unsigned pk_[8];                                                           \
    _Pragma("unroll") for (int i_ = 0; i_ < 8; ++i_)                           \
        pk_[i_] = cvt_pk_bf16(p_[2 * i_], p_[2 * i_ + 1]);                     \
    auto a0_ = __builtin_amdgcn_permlane32_swap(pk_[0], pk_[2], false, false); \
    auto a1_ = __builtin_amdgcn_permlane32_swap(pk_[1], pk_[3], false, false); \
    auto a2_ = __builtin_amdgcn_permlane32_swap(pk_[4], pk_[6], false, false); \
    auto a3_ = __builtin_amdgcn_permlane32_swap(pk_[5], pk_[7], false, false); \
    PWV[0][0] = a0_[0]; PWV[0][1] = a1_[0]; PWV[0][2] = a0_[1];                \
    PWV[0][3] = a1_[1]; PWV[1][0] = a2_[0]; PWV[1][1] = a3_[0];                \
    PWV[1][2] = a2_[1]; PWV[1][3] = a3_[1];                                    \
  } while (0)

// ---------------- kernel 2: fused leaky(mask(Q K^T)) @ V + base ----------------
__global__ __launch_bounds__(256) void attn_kernel(
    const u16* __restrict__ Kbf, const u16* __restrict__ Vt,
    const u16* __restrict__ Bb, const float* __restrict__ scal_ws,
    float* __restrict__ Hout) {
  __shared__ __align__(16) u16 Qla[2][64 * 64];
  __shared__ __align__(16) u16 KV[3][2][64 * 64];
  __shared__ float Ol[128 * 65];
  __shared__ float sc[64];

  const int t = threadIdx.x;
  const int b = blockIdx.x;        // batch: consecutive blocks share XCD L2 per batch
  const int q0 = blockIdx.y * 128; // q tile within batch
  const int lane = t & 63, w = t >> 6, h = lane >> 5, ln = lane & 31;
  const int qrow = w * 32 + ln;

  const u16* Kg = Kbf + (size_t)b * 65536;
  const u16* Vg = Vt + (size_t)b * 65536;

  if (t < 64) sc[t] = scal_ws[t];

  // prologue staging: Q tile (2 halves from K array) + KV tile 0
  stage_tile64(Kg + (size_t)q0 * 64, 64, Qla[0], t);
  stage_tile64(Kg + (size_t)(q0 + 64) * 64, 64, Qla[1], t);
  stage_tile64(Kg, 64, KV[0][0], t);
  stage_tile64(Vg, 1024, KV[0][1], t);
  WAIT_VMCNT(4);  // Q halves done; KV0's 4 may remain in flight
  __builtin_amdgcn_s_barrier();
  CFENCE;

  // Q frags = K rows scaled by sc[g] (Q = attX * scale)
  s16x8 qf[4];
  #pragma unroll
  for (int ks = 0; ks < 4; ++ks) {
    s16x8 q = frag(Qla[w >> 1], qrow & 63, ks * 2 + h);
    union { unsigned u[4]; s16x8 v; } qq;
    #pragma unroll
    for (int j = 0; j < 4; ++j) {
      float lo = bf2f((u16)q[2 * j]) * sc[ks * 16 + h * 8 + 2 * j];
      float hi = bf2f((u16)q[2 * j + 1]) * sc[ks * 16 + h * 8 + 2 * j + 1];
      qq.u[j] = cvt_pk_bf16(lo, hi);
    }
    qf[ks] = qq.v;
  }

  f32x16 o0 = zero16(), o1 = zero16();

  #pragma unroll
  for (int tix = 0; tix < 16; ++tix) {
    const int kv0 = tix * 64;
    if (tix < 15) {
      const int ns = (tix + 1) % 3;
      stage_tile64(Kg + (size_t)(kv0 + 64) * 64, 64, KV[ns][0], t);
      stage_tile64(Vg + (kv0 + 64), 1024, KV[ns][1], t);
      WAIT_VMCNT(4);  // tile tix staged; next tile's 4 stay in flight
    } else {
      WAIT_VMCNT(0);
    }
    __builtin_amdgcn_s_barrier();
    CFENCE;
    const u16* Kl = KV[tix % 3][0];
    const u16* Vl = KV[tix % 3][1];

    // S^T = K * Q^T : two interleaved accumulation chains
    f32x16 s0 = zero16(), s1 = zero16();
    __builtin_amdgcn_s_setprio(1);
    #pragma unroll
    for (int ks = 0; ks < 4; ++ks) {
      s0 = __builtin_amdgcn_mfma_f32_32x32x16_bf16(frag(Kl, ln, ks * 2 + h), qf[ks], s0, 0, 0, 0);
      s1 = __builtin_amdgcn_mfma_f32_32x32x16_bf16(frag(Kl, 32 + ln, ks * 2 + h), qf[ks], s1, 0, 0, 0);
    }
    __builtin_amdgcn_s_setprio(0);

    const bool dg0 = (kv0 == q0 + w * 32);       // rf0 tile aligns with wave's q rows
    const bool dg1 = (kv0 + 32 == q0 + w * 32);  // rf1
    unsigned pw0[2][4], pw1[2][4];
    PROC(s0, dg0, pw0);
    PROC(s1, dg1, pw1);

    // O^T += V^T * P^T
    __builtin_amdgcn_s_setprio(1);
    #pragma unroll
    for (int kk = 0; kk < 4; ++kk) {
      union { unsigned u[4]; s16x8 v; } pb;
      pb.u[0] = (kk < 2 ? pw0 : pw1)[kk & 1][0];
      pb.u[1] = (kk < 2 ? pw0 : pw1)[kk & 1][1];
      pb.u[2] = (kk < 2 ? pw0 : pw1)[kk & 1][2];
      pb.u[3] = (kk < 2 ? pw0 : pw1)[kk & 1][3];
      o0 = __builtin_amdgcn_mfma_f32_32x32x16_bf16(frag(Vl, ln, kk * 2 + h), pb.v, o0, 0, 0, 0);
      o1 = __builtin_amdgcn_mfma_f32_32x32x16_bf16(frag(Vl, 32 + ln, kk * 2 + h), pb.v, o1, 0, 0, 0);
    }
    __builtin_amdgcn_s_setprio(0);
  }

  // epilogue: O^T regs -> Ol[q][d] -> coalesced float4 write with bf16 base add
  #pragma unroll
  for (int reg = 0; reg < 16; ++reg) {
    int dd = (reg & 3) + 8 * (reg >> 2) + 4 * h;
    Ol[(w * 32 + ln) * 65 + dd] = o0[reg];
    Ol[(w * 32 + ln) * 65 + 32 + dd] = o1[reg];
  }
  __syncthreads();
  #pragma unroll
  for (int i = 0; i < 8; ++i) {
    int fi = i * 256 + t;
    int q = fi >> 4, dw = (fi & 15) * 4;
    float4 v = {Ol[q * 65 + dw], Ol[q * 65 + dw + 1], Ol[q * 65 + dw + 2], Ol[q * 65 + dw + 3]};
    size_t go = ((size_t)b * 1024 + q0 + q) * 64 + dw;
    const short4 bv = *(const short4*)(Bb + go);
    v.x += bf2f((u16)bv.x);
    v.y += bf2f((u16)bv.y);
    v.z += bf2f((u16)bv.z);
    v.w += bf2f((u16)bv.w);
    *(float4*)(Hout + go) = v;
  }
}

extern "C" void kernel_launch(void* const* d_in, const int* in_sizes, int n_in,
                              void* d_out, int out_size, void* d_ws, size_t ws_size,
                              hipStream_t stream) {
  const float* X = (const float*)d_in[0];
  // d_in[1] = A : unused by the forward pass
  const float* W = (const float*)d_in[2];
  const float* attW = (const float*)d_in[3];
  const float* a = (const float*)d_in[4];
  const float* biasW = (const float*)d_in[5];
  const float* selfW = (const float*)d_in[6];
  float* H = (float*)d_out;

  u16* Kbf = (u16*)d_ws;                               // 32*1024*64 bf16 = 4 MB
  u16* Vt = Kbf + (size_t)32 * 1024 * 64;              // 4 MB
  u16* Bb = Vt + (size_t)32 * 1024 * 64;               // 4 MB region (uses 4 MB? 2MB: 32*1024*64 bf16)
  float* scal = (float*)(Bb + (size_t)32 * 1024 * 64); // 256 B

  prep_kernel<<<256, 256, 0, stream>>>(X, W, attW, a, biasW, selfW, Kbf, Vt, Bb, scal);
  attn_kernel<<<dim3(32, 8), 256, 0, stream>>>(Kbf, Vt, Bb, scal, H);
}

// Round 4
// 35.628 us; speedup vs baseline: 1.2151x; 1.0191x over previous
//
#include <hip/hip_runtime.h>

#define DEV __device__ __forceinline__
typedef short s16x8 __attribute__((ext_vector_type(8)));
typedef float f32x16 __attribute__((ext_vector_type(16)));
typedef unsigned short u16;

#define WAIT_VMCNT(N) asm volatile("s_waitcnt vmcnt(" #N ")" ::: "memory")
#define CFENCE asm volatile("" ::: "memory")

DEV unsigned cvt_pk_bf16(float lo, float hi) {
  unsigned r;
  asm volatile("v_cvt_pk_bf16_f32 %0, %1, %2" : "=v"(r) : "v"(lo), "v"(hi));
  return r;
}
DEV u16 f2bf(float f) {
  unsigned u = __builtin_bit_cast(unsigned, f);
  unsigned r = u + 0x7fffu + ((u >> 16) & 1u);
  return (u16)(r >> 16);
}
DEV float bf2f(u16 u) { return __builtin_bit_cast(float, (unsigned)u << 16); }
DEV f32x16 zero16() {
  f32x16 v;
  #pragma unroll
  for (int i = 0; i < 16; ++i) v[i] = 0.f;
  return v;
}

// async global->LDS: 16B per lane, LDS dest = wave-uniform base + lane*16
DEV void gld16(const u16* g, u16* l) {
  __builtin_amdgcn_global_load_lds(
      (const __attribute__((address_space(1))) void*)g,
      (__attribute__((address_space(3))) void*)l, 16, 0, 0);
}

// stage 64x64 bf16 tile (row stride `stride`) into frag-swizzled LDS (2 issues/thread)
DEV void stage_tile64(const u16* __restrict__ gbase, size_t stride, u16* lbuf, int t) {
  #pragma unroll
  for (int p = 0; p < 2; ++p) {
    int c = p * 256 + t;
    int row = c >> 3, s = c & 7;
    int gck = s ^ (row & 7);
    const u16* src = gbase + (size_t)row * stride + gck * 8;
    u16* dst = lbuf + (size_t)(p * 256 + (t & 192)) * 8;  // wave-uniform base
    gld16(src, dst);
  }
}

DEV s16x8 frag(const u16* buf, int row, int chunk) {
  return *(const s16x8*)(buf + row * 64 + ((chunk ^ (row & 7)) << 3));
}

DEV int kswz(int row, int d) {  // scalar-element address in frag-swizzled 64x64 tile
  return row * 64 + ((((d >> 3) ^ (row & 7)) << 3) | (d & 7));
}

DEV void stage_wt(const float* __restrict__ src, u16* dst, int t) {
  // src: [64 f][64 g] f32 row-major -> dst[g][f] bf16, frag-swizzled
  #pragma unroll
  for (int r = 0; r < 4; ++r) {
    int e = (r * 256 + t) * 4;
    int f = e >> 6, g0 = e & 63;
    float4 v = *(const float4*)(src + f * 64 + g0);
    float vv[4] = {v.x, v.y, v.z, v.w};
    #pragma unroll
    for (int j = 0; j < 4; ++j) {
      int g = g0 + j;
      dst[g * 64 + ((((f >> 3) ^ (g & 7)) << 3) | (f & 7))] = f2bf(vv[j]);
    }
  }
}

// ---------------- kernel 1: projections (64 rows/block, 512 blocks) ----------------
__global__ __launch_bounds__(256) void prep_kernel(
    const float* __restrict__ X, const float* __restrict__ W,
    const float* __restrict__ attW, const float* __restrict__ Aa,
    const float* __restrict__ biasW, const float* __restrict__ selfW,
    u16* __restrict__ Kbf, u16* __restrict__ Vt, u16* __restrict__ Bb,
    float* __restrict__ scal_ws) {
  __shared__ __align__(16) u16 Xl[64 * 64];  // reused for K output
  __shared__ __align__(16) u16 Wt[3][64 * 64];
  __shared__ __align__(16) u16 Bl[64 * 64];
  __shared__ __align__(16) u16 Vl[64 * 72];  // 144B row stride
  __shared__ float sc4[4][64];

  const int t = threadIdx.x;
  const int r0 = blockIdx.x * 64;
  const int b = r0 >> 10;
  const int n0 = r0 & 1023;

  if (blockIdx.x == 0) {  // scale = a.sum(axis=0), one block only
    int qt = t >> 6, d = t & 63;
    float s = 0.f;
    #pragma unroll
    for (int i = 0; i < 16; ++i) s += Aa[(qt * 16 + i) * 64 + d];
    sc4[qt][d] = s;
  }

  // stage X tile 64x64 f32 -> bf16 frag-swizzled
  #pragma unroll
  for (int p = 0; p < 2; ++p) {
    int c = p * 256 + t;
    int row = c >> 3, ck = c & 7;
    const float4* src = (const float4*)(X + (size_t)(r0 + row) * 64 + ck * 8);
    float4 a0 = src[0], a1 = src[1];
    unsigned* dst = (unsigned*)&Xl[row * 64 + ((ck ^ (row & 7)) << 3)];
    dst[0] = cvt_pk_bf16(a0.x, a0.y);
    dst[1] = cvt_pk_bf16(a0.z, a0.w);
    dst[2] = cvt_pk_bf16(a1.x, a1.y);
    dst[3] = cvt_pk_bf16(a1.z, a1.w);
  }
  stage_wt(attW, &Wt[0][0], t);
  stage_wt(W, &Wt[1][0], t);
  stage_wt(selfW, &Wt[2][0], t);
  __syncthreads();

  const int lane = t & 63, w = t >> 6, h = lane >> 5, ln = lane & 31;
  const int rg = (w >> 1) * 32;  // row group
  const int cf = w & 1;          // col half
  const int d = cf * 32 + ln;

  s16x8 xa[4];
  #pragma unroll
  for (int ks = 0; ks < 4; ++ks) xa[ks] = frag(Xl, rg + ln, ks * 2 + h);

  f32x16 aA = zero16(), aW = zero16(), aS = zero16();
  #pragma unroll
  for (int ks = 0; ks < 4; ++ks) {
    s16x8 bA = frag(&Wt[0][0], d, ks * 2 + h);
    s16x8 bW = frag(&Wt[1][0], d, ks * 2 + h);
    s16x8 bS = frag(&Wt[2][0], d, ks * 2 + h);
    aA = __builtin_amdgcn_mfma_f32_32x32x16_bf16(xa[ks], bA, aA, 0, 0, 0);
    aW = __builtin_amdgcn_mfma_f32_32x32x16_bf16(xa[ks], bW, aW, 0, 0, 0);
    aS = __builtin_amdgcn_mfma_f32_32x32x16_bf16(xa[ks], bS, aS, 0, 0, 0);
  }
  __syncthreads();  // all waves done reading Xl before K overwrites it

  const float bi = biasW[d];
  #pragma unroll
  for (int reg = 0; reg < 16; ++reg) {
    int rl = (reg & 3) + 8 * (reg >> 2) + 4 * h;
    int row = rg + rl;
    Xl[kswz(row, d)] = f2bf(aA[reg]);       // K tile
    Bl[kswz(row, d)] = f2bf(aS[reg] + bi);  // base tile
  }
  #pragma unroll
  for (int pg = 0; pg < 4; ++pg) {
    int n = rg + pg * 8 + 4 * h;
    *(unsigned*)&Vl[d * 72 + n] = cvt_pk_bf16(aW[pg * 4 + 0], aW[pg * 4 + 1]);
    *(unsigned*)&Vl[d * 72 + n + 2] = cvt_pk_bf16(aW[pg * 4 + 2], aW[pg * 4 + 3]);
  }
  __syncthreads();

  // vectorized global writes
  #pragma unroll
  for (int p = 0; p < 2; ++p) {
    int c = p * 256 + t;
    int row = c >> 3, ck = c & 7;
    size_t go = (size_t)(r0 + row) * 64 + ck * 8;
    *(s16x8*)&Kbf[go] = *(const s16x8*)&Xl[row * 64 + ((ck ^ (row & 7)) << 3)];
    *(s16x8*)&Bb[go] = *(const s16x8*)&Bl[row * 64 + ((ck ^ (row & 7)) << 3)];
  }
  #pragma unroll
  for (int p = 0; p < 2; ++p) {
    int c = p * 256 + t;
    int dd = c >> 3, ck = c & 7;
    *(s16x8*)&Vt[(size_t)(b * 64 + dd) * 1024 + n0 + ck * 8] =
        *(const s16x8*)&Vl[dd * 72 + ck * 8];
  }
  if (blockIdx.x == 0 && t < 64)
    scal_ws[t] = sc4[0][t] + sc4[1][t] + sc4[2][t] + sc4[3][t];
}

// P-processing: leaky + optional diag-zero + pack to P^T B-frag words
#define PROC(SV, DG, PWV)                                                      \
  do {                                                                         \
    float p_[16];                                                              \
    _Pragma("unroll") for (int r_ = 0; r_ < 16; ++r_) {                        \
      float v_ = (SV)[r_];                                                     \
      p_[r_] = fmaxf(v_, 0.f) + 0.01f * fminf(v_, 0.f);                        \
    }                                                                          \
    if (DG) {                                                                  \
      _Pragma("unroll") for (int r_ = 0; r_ < 16; ++r_) {                      \
        int rl_ = (r_ & 3) + 8 * (r_ >> 2) + 4 * h;                            \
        p_[r_] = (rl_ == ln) ? 0.f : p_[r_];                                   \
      }                                                                        \
    }                                                                          \
    unsigned pk_[8];                                                           \
    _Pragma("unroll") for (int i_ = 0; i_ < 8; ++i_)                           \
        pk_[i_] = cvt_pk_bf16(p_[2 * i_], p_[2 * i_ + 1]);                     \
    auto a0_ = __builtin_amdgcn_permlane32_swap(pk_[0], pk_[2], false, false); \
    auto a1_ = __builtin_amdgcn_permlane32_swap(pk_[1], pk_[3], false, false); \
    auto a2_ = __builtin_amdgcn_permlane32_swap(pk_[4], pk_[6], false, false); \
    auto a3_ = __builtin_amdgcn_permlane32_swap(pk_[5], pk_[7], false, false); \
    PWV[0][0] = a0_[0]; PWV[0][1] = a1_[0]; PWV[0][2] = a0_[1];                \
    PWV[0][3] = a1_[1]; PWV[1][0] = a2_[0]; PWV[1][1] = a3_[0];                \
    PWV[1][2] = a2_[1]; PWV[1][3] = a3_[1];                                    \
  } while (0)

// ---------------- kernel 2: fused leaky(mask(Q K^T)) @ V + base ----------------
// 512 blocks (32 batches x 16 q-tiles of 64), 4 waves = (q-half, kv-half)
__global__ __launch_bounds__(256) void attn_kernel(
    const u16* __restrict__ Kbf, const u16* __restrict__ Vt,
    const u16* __restrict__ Bb, const float* __restrict__ scal_ws,
    float* __restrict__ Hout) {
  __shared__ __align__(16) u16 KV[4][2][64 * 64];  // 64 KB ring-4 (K,V per slot)
  __shared__ float sc[64];
  float* Ol0 = (float*)&KV[0][0][0];  // 16 KB O-partial (kv-half 0); safe: slot0 last read at tile 12
  float* Ol1 = (float*)&KV[1][0][0];  // kv-half 1; slot1 last read at tile 13

  const int t = threadIdx.x;
  const int b = blockIdx.x;         // linear-id%8 == b%8 -> per-batch XCD L2 locality
  const int q0 = blockIdx.y * 64;
  const int lane = t & 63, w = t >> 6, h = lane >> 5, ln = lane & 31;
  const int qh = w & 1, kvh = w >> 1;
  const int qg = q0 + qh * 32 + ln;  // this lane's q row

  const u16* Kg = Kbf + (size_t)b * 65536;
  const u16* Vg = Vt + (size_t)b * 65536;

  // Q rows direct global->reg (L2-hot, one-time)
  s16x8 qraw[4];
  #pragma unroll
  for (int ks = 0; ks < 4; ++ks)
    qraw[ks] = *(const s16x8*)(Kg + (size_t)qg * 64 + ks * 16 + h * 8);
  float scv = 0.f;
  if (t < 64) scv = scal_ws[t];

  // prologue: stage tiles 0,1 (8 issues/thread)
  stage_tile64(Kg, 64, &KV[0][0][0], t);
  stage_tile64(Vg, 1024, &KV[0][1][0], t);
  stage_tile64(Kg + (size_t)64 * 64, 64, &KV[1][0][0], t);
  stage_tile64(Vg + 64, 1024, &KV[1][1][0], t);

  if (t < 64) sc[t] = scv;
  asm volatile("s_waitcnt lgkmcnt(0)" ::: "memory");
  __builtin_amdgcn_s_barrier();  // sc visible; does NOT drain vmcnt
  CFENCE;

  // qf = Q^T B-frags scaled per-feature
  s16x8 qf[4];
  #pragma unroll
  for (int ks = 0; ks < 4; ++ks) {
    float4 s0 = *(const float4*)&sc[ks * 16 + h * 8];
    float4 s1 = *(const float4*)&sc[ks * 16 + h * 8 + 4];
    union { unsigned u[4]; s16x8 v; } qq;
    qq.u[0] = cvt_pk_bf16(bf2f((u16)qraw[ks][0]) * s0.x, bf2f((u16)qraw[ks][1]) * s0.y);
    qq.u[1] = cvt_pk_bf16(bf2f((u16)qraw[ks][2]) * s0.z, bf2f((u16)qraw[ks][3]) * s0.w);
    qq.u[2] = cvt_pk_bf16(bf2f((u16)qraw[ks][4]) * s1.x, bf2f((u16)qraw[ks][5]) * s1.y);
    qq.u[3] = cvt_pk_bf16(bf2f((u16)qraw[ks][6]) * s1.z, bf2f((u16)qraw[ks][7]) * s1.w);
    qf[ks] = qq.v;
  }

  f32x16 o0 = zero16(), o1 = zero16();

  #pragma unroll 1
  for (int tix = 0; tix < 16; ++tix) {
    const int kv0 = tix * 64;
    if (tix < 14) {  // depth-2 prefetch into (tix+2)&3 — safe: prev iter reads (tix-1)&3
      const int ns = (tix + 2) & 3;
      stage_tile64(Kg + (size_t)(kv0 + 128) * 64, 64, &KV[ns][0][0], t);
      stage_tile64(Vg + (kv0 + 128), 1024, &KV[ns][1][0], t);
      WAIT_VMCNT(8);  // tile tix complete; tiles tix+1, tix+2 in flight
    } else if (tix == 14) {
      WAIT_VMCNT(4);
    } else {
      WAIT_VMCNT(0);
    }
    __builtin_amdgcn_s_barrier();
    CFENCE;
    const u16* Kl = &KV[tix & 3][0][0];
    const u16* Vl = &KV[tix & 3][1][0];

    // S^T quarter [kv-half][q-half]: 4 MFMAs over K=64
    f32x16 s = zero16();
    __builtin_amdgcn_s_setprio(1);
    #pragma unroll
    for (int ks = 0; ks < 4; ++ks)
      s = __builtin_amdgcn_mfma_f32_32x32x16_bf16(frag(Kl, kvh * 32 + ln, ks * 2 + h), qf[ks], s, 0, 0, 0);
    __builtin_amdgcn_s_setprio(0);

    const bool dg = (kv0 + kvh * 32) == (q0 + qh * 32);
    unsigned pw[2][4];
    PROC(s, dg, pw);

    // O^T partial += V^T[:, kv-half] * P^T
    __builtin_amdgcn_s_setprio(1);
    #pragma unroll
    for (int kk = 0; kk < 2; ++kk) {
      union { unsigned u[4]; s16x8 v; } pb;
      pb.u[0] = pw[kk][0]; pb.u[1] = pw[kk][1];
      pb.u[2] = pw[kk][2]; pb.u[3] = pw[kk][3];
      int ch = kvh * 4 + kk * 2 + h;
      o0 = __builtin_amdgcn_mfma_f32_32x32x16_bf16(frag(Vl, ln, ch), pb.v, o0, 0, 0, 0);
      o1 = __builtin_amdgcn_mfma_f32_32x32x16_bf16(frag(Vl, 32 + ln, ch), pb.v, o1, 0, 0, 0);
    }
    __builtin_amdgcn_s_setprio(0);
  }

  // epilogue: write O partials (granule-swizzled, no padding), reduce, add base, store
  float* Od = kvh ? Ol1 : Ol0;
  const int q = qh * 32 + ln;
  #pragma unroll
  for (int reg = 0; reg < 16; ++reg) {
    int rl = (reg & 3) + 8 * (reg >> 2) + 4 * h;
    int d0 = rl, d1 = 32 + rl;
    Od[q * 64 + ((((d0 >> 2) ^ (q & 15)) << 2) | (d0 & 3))] = o0[reg];
    Od[q * 64 + ((((d1 >> 2) ^ (q & 15)) << 2) | (d1 & 3))] = o1[reg];
  }
  __syncthreads();
  #pragma unroll
  for (int i = 0; i < 4; ++i) {
    int fi = i * 256 + t;
    int qq = fi >> 4, g = fi & 15;
    int off = qq * 64 + ((g ^ (qq & 15)) << 2);
    float4 v0 = *(const float4*)&Ol0[off];
    float4 v1 = *(const float4*)&Ol1[off];
    size_t go = ((size_t)b * 1024 + q0 + qq) * 64 + g * 4;
    const short4 bv = *(const short4*)(Bb + go);
    float4 v;
    v.x = v0.x + v1.x + bf2f((u16)bv.x);
    v.y = v0.y + v1.y + bf2f((u16)bv.y);
    v.z = v0.z + v1.z + bf2f((u16)bv.z);
    v.w = v0.w + v1.w + bf2f((u16)bv.w);
    *(float4*)(Hout + go) = v;
  }
}

extern "C" void kernel_launch(void* const* d_in, const int* in_sizes, int n_in,
                              void* d_out, int out_size, void* d_ws, size_t ws_size,
                              hipStream_t stream) {
  const float* X = (const float*)d_in[0];
  // d_in[1] = A : unused by the forward pass
  const float* W = (const float*)d_in[2];
  const float* attW = (const float*)d_in[3];
  const float* a = (const float*)d_in[4];
  const float* biasW = (const float*)d_in[5];
  const float* selfW = (const float*)d_in[6];
  float* H = (float*)d_out;

  u16* Kbf = (u16*)d_ws;                                // 4 MB
  u16* Vt = Kbf + (size_t)32 * 1024 * 64;               // 4 MB
  u16* Bb = Vt + (size_t)32 * 1024 * 64;                // 4 MB
  float* scal = (float*)(Bb + (size_t)32 * 1024 * 64);  // 256 B

  prep_kernel<<<512, 256, 0, stream>>>(X, W, attW, a, biasW, selfW, Kbf, Vt, Bb, scal);
  attn_kernel<<<dim3(32, 16), 256, 0, stream>>>(Kbf, Vt, Bb, scal, H);
}